// Round 2
// baseline (366.581 us; speedup 1.0000x reference)
//
#include <hip/hip_runtime.h>
#include <hip/hip_bf16.h>
#include <stdint.h>

#define DIM   512
#define INNER 512
#define HEADS 8
#define DH    64
#define B_    4
#define N_    2048
#define ROWS  (B_*N_)     // 8192
#define QKVN  (3*INNER)   // 1536

typedef __attribute__((ext_vector_type(8))) short bf8_t;  // 8 bf16 (4 VGPRs)
typedef __attribute__((ext_vector_type(4))) float f4_t;   // MFMA C/D

__device__ __forceinline__ unsigned short f2bf(float f){
  union { float f; unsigned u; } x; x.f = f;
  unsigned u = x.u;
  return (unsigned short)((u + 0x7fffu + ((u >> 16) & 1u)) >> 16);  // RTNE
}
__device__ __forceinline__ float bf2f(unsigned short h){
  union { unsigned u; float f; } x; x.u = ((unsigned)h) << 16; return x.f;
}

// ---------------- LayerNorm: fp32 [8192,512] -> bf16 xn ----------------
__global__ __launch_bounds__(128)
void ln_kernel(const float* __restrict__ x, const float* __restrict__ g,
               const float* __restrict__ b, unsigned short* __restrict__ xn)
{
  const int row = blockIdx.x;
  const int t = threadIdx.x;
  const float4 v = ((const float4*)(x + (size_t)row*DIM))[t];
  float s  = v.x + v.y + v.z + v.w;
  float s2 = v.x*v.x + v.y*v.y + v.z*v.z + v.w*v.w;
  #pragma unroll
  for (int d = 32; d >= 1; d >>= 1){ s += __shfl_down(s, d); s2 += __shfl_down(s2, d); }
  __shared__ float ps[2], ps2[2];
  if ((t & 63) == 0){ ps[t >> 6] = s; ps2[t >> 6] = s2; }
  __syncthreads();
  const float mu  = (ps[0] + ps[1]) * (1.f/DIM);
  const float var = (ps2[0] + ps2[1]) * (1.f/DIM) - mu*mu;
  const float rs  = rsqrtf(var + 1e-5f);
  const float4 gm = ((const float4*)g)[t];
  const float4 bt = ((const float4*)b)[t];
  unsigned long long pk =
      (unsigned long long)f2bf((v.x-mu)*rs*gm.x + bt.x)
    | ((unsigned long long)f2bf((v.y-mu)*rs*gm.y + bt.y) << 16)
    | ((unsigned long long)f2bf((v.z-mu)*rs*gm.z + bt.z) << 32)
    | ((unsigned long long)f2bf((v.w-mu)*rs*gm.w + bt.w) << 48);
  *(unsigned long long*)(xn + (size_t)row*DIM + t*4) = pk;
}

// ---------- transpose fp32 W[R][C] -> bf16 WT[C][R] (LDS-tiled) ----------
__global__ __launch_bounds__(256)
void transpose_f32_to_bf16T(const float* __restrict__ W, unsigned short* __restrict__ WT,
                            int R, int C)
{
  __shared__ float tile[32][33];
  const int bc = blockIdx.x*32, br = blockIdx.y*32;
  const int tx = threadIdx.x & 31, ty = threadIdx.x >> 5;  // ty 0..7
  #pragma unroll
  for (int i = 0; i < 32; i += 8) tile[ty+i][tx] = W[(size_t)(br+ty+i)*C + bc+tx];
  __syncthreads();
  #pragma unroll
  for (int i = 0; i < 32; i += 8) WT[(size_t)(bc+ty+i)*R + br+tx] = f2bf(tile[tx][ty+i]);
}

// ---------------- RoPE sin/cos table [2048][64] fp32 ----------------
__global__ __launch_bounds__(256)
void rope_table(float* __restrict__ sin_t, float* __restrict__ cos_t)
{
  const int idx = blockIdx.x*256 + threadIdx.x;     // exactly 2048*64
  const int pos = idx >> 6, i = idx & 63;
  const float freq = expf((float)i * (-9.210340371976184f / 64.f)); // 10000^(-i/64)
  const float ang  = (float)pos * freq;
  sin_t[idx] = sinf(ang);
  cos_t[idx] = cosf(ang);
}

// --------- GEMM: C[M,N] = A[M,K]bf16 * BT[N,K]bf16  (128x128 tile, BK=32) ---------
template<int OUT_BF16, int ADD_BIAS>
__global__ __launch_bounds__(256)
void gemm128(const unsigned short* __restrict__ A, const unsigned short* __restrict__ BT,
             void* __restrict__ Cout, const float* __restrict__ bias, int M, int N, int K)
{
  __shared__ unsigned short Asm_[128*32];
  __shared__ unsigned short Bsm_[128*32];
  const int t = threadIdx.x;
  const int lane = t & 63, w = t >> 6;
  const int g = lane >> 4, r16 = lane & 15;
  const size_t bm = (size_t)blockIdx.x * 128, bn = (size_t)blockIdx.y * 128;
  const int wm = (w >> 1) * 64, wn = (w & 1) * 64;
  f4_t acc[4][4] = {};

  int aoff[4], boff[4];
  #pragma unroll
  for (int m = 0; m < 4; ++m){
    const int row = wm + m*16 + r16;
    aoff[m] = (row*4 + (g ^ ((row >> 1) & 3))) * 16;
    const int col = wn + m*16 + r16;
    boff[m] = (col*4 + (g ^ ((col >> 1) & 3))) * 16;
  }
  int srow[2], scol[2];
  #pragma unroll
  for (int rd = 0; rd < 2; ++rd){
    const int slot = rd*256 + t;
    srow[rd] = slot >> 2;
    scol[rd] = ((slot & 3) ^ ((srow[rd] >> 1) & 3)) * 8;
  }

  for (int k0 = 0; k0 < K; k0 += 32){
    #pragma unroll
    for (int rd = 0; rd < 2; ++rd){
      const unsigned short* ga = A  + (bm + srow[rd])*K + k0 + scol[rd];
      const unsigned short* gb = BT + (bn + srow[rd])*K + k0 + scol[rd];
      __builtin_amdgcn_global_load_lds((const __attribute__((address_space(1))) void*)ga,
          (__attribute__((address_space(3))) void*)((char*)Asm_ + (rd*256 + w*64)*16), 16, 0, 0);
      __builtin_amdgcn_global_load_lds((const __attribute__((address_space(1))) void*)gb,
          (__attribute__((address_space(3))) void*)((char*)Bsm_ + (rd*256 + w*64)*16), 16, 0, 0);
    }
    __syncthreads();
    bf8_t af[4], bfr[4];
    #pragma unroll
    for (int m = 0; m < 4; ++m) af[m]  = *(const bf8_t*)((const char*)Asm_ + aoff[m]);
    #pragma unroll
    for (int n = 0; n < 4; ++n) bfr[n] = *(const bf8_t*)((const char*)Bsm_ + boff[n]);
    #pragma unroll
    for (int m = 0; m < 4; ++m)
      #pragma unroll
      for (int n = 0; n < 4; ++n)
        acc[m][n] = __builtin_amdgcn_mfma_f32_16x16x32_bf16(af[m], bfr[n], acc[m][n], 0, 0, 0);
    __syncthreads();
  }

  #pragma unroll
  for (int m = 0; m < 4; ++m)
    #pragma unroll
    for (int n = 0; n < 4; ++n)
      #pragma unroll
      for (int r = 0; r < 4; ++r){
        const size_t row = bm + wm + m*16 + g*4 + r;
        const size_t col = bn + wn + n*16 + r16;
        float v = acc[m][n][r];
        if (ADD_BIAS) v += bias[col];
        if (OUT_BF16) ((unsigned short*)Cout)[row*N + col] = f2bf(v);
        else          ((float*)Cout)[row*N + col] = v;
      }
}

// ---------- RoPE apply + head relayout: qkv[8192][1536] -> Qh/Kh/Vh [32][2048][64] ----------
// Q is pre-scaled by dh^-0.5 = 0.125 (exponent-exact in bf16).
__global__ __launch_bounds__(256)
void rope_apply(const unsigned short* __restrict__ qkv, const float* __restrict__ sin_t,
                const float* __restrict__ cos_t, unsigned short* __restrict__ Qh,
                unsigned short* __restrict__ Kh, unsigned short* __restrict__ Vh)
{
  const int wid  = blockIdx.x*4 + (threadIdx.x >> 6);   // one wave per (bh, n)
  const int lane = threadIdx.x & 63;
  const int n  = wid & (N_-1);
  const int bh = wid >> 11;
  const int h = bh & 7, b = bh >> 3;
  const size_t src = ((size_t)(b*N_ + n))*QKVN + h*DH + lane;
  const float q = bf2f(qkv[src]);
  const float k = bf2f(qkv[src + INNER]);
  const unsigned short v = qkv[src + 2*INNER];
  const float qm = __shfl(q, (lane + 63) & 63);   // roll(x,1,-1)
  const float km = __shfl(k, (lane + 63) & 63);
  const float sn = sin_t[n*DH + lane], cs = cos_t[n*DH + lane];
  const size_t dst = ((size_t)bh*N_ + n)*DH + lane;
  Qh[dst] = f2bf((q*cs + qm*sn) * 0.125f);
  Kh[dst] = f2bf(k*cs + km*sn);
  Vh[dst] = v;
}

// ---------- V transpose per head: Vh[bh][n][d] -> Vt[bh][d][n] ----------
__global__ __launch_bounds__(256)
void v_transpose(const unsigned short* __restrict__ Vh, unsigned short* __restrict__ Vt)
{
  __shared__ unsigned short tile[64][72];   // pad 8 shorts: keeps 16B alignment
  const int bh = blockIdx.y, n0 = blockIdx.x*64;
  const int t = threadIdx.x;
  const size_t base = (size_t)bh*N_*DH;
  {   // load 64 n-rows x 64 d, coalesced 32B per thread
    const int r = t >> 2, seg = t & 3;
    const uint4* src = (const uint4*)(Vh + base + (size_t)(n0 + r)*DH + seg*16);
    *(uint4*)&tile[r][seg*16]     = src[0];
    *(uint4*)&tile[r][seg*16 + 8] = src[1];
  }
  __syncthreads();
  {   // write: lane d reads tile[n][d] (row-contig across lanes -> conflict-free)
    const int d = t & 63, wv = t >> 6;
    unsigned short tmp[16];
    #pragma unroll
    for (int e = 0; e < 16; ++e) tmp[e] = tile[wv*16 + e][d];
    uint4* dst = (uint4*)(Vt + base + (size_t)d*N_ + n0 + wv*16);
    dst[0] = *(uint4*)&tmp[0];
    dst[1] = *(uint4*)&tmp[8];
  }
}

// ---------------- flash attention v2: no K/V LDS staging, no barriers ----------------
// K frags + V^T frags read directly from global (L2-resident, XCD-grouped by bh).
__global__ __launch_bounds__(256)
void flash_attn2(const unsigned short* __restrict__ Qh, const unsigned short* __restrict__ Kh,
                 const unsigned short* __restrict__ Vt, unsigned short* __restrict__ Oh)
{
  __shared__ unsigned short Psm[4][16*64];   // per-wave P buffer, XOR-swizzled
  const int t = threadIdx.x, lane = t & 63, w = t >> 6;
  const int g = lane >> 4, r16 = lane & 15;
  const int i = blockIdx.x;
  const int bh = (i & 7)*4 + (i >> 8);   // 4 heads per XCD -> 2MB K+V in XCD L2
  const int qt = (i >> 3) & 31;
  const size_t base = (size_t)bh * (N_*DH);
  const int q0 = qt*64 + w*16;

  bf8_t qa[2];   // Q A-frags (pre-scaled), held for the whole loop
  #pragma unroll
  for (int kc = 0; kc < 2; ++kc)
    qa[kc] = *(const bf8_t*)(Qh + base + (size_t)(q0 + r16)*DH + kc*32 + g*8);

  f4_t oacc[4] = {};
  float mrow[4] = {-1e30f, -1e30f, -1e30f, -1e30f};
  float lrow[4] = {0.f, 0.f, 0.f, 0.f};

  // kt-invariant LDS byte offsets for the P roundtrip
  unsigned pwoff[4][4];
  #pragma unroll
  for (int j = 0; j < 4; ++j)
    #pragma unroll
    for (int r = 0; r < 4; ++r){
      const int row = g*4 + r;
      pwoff[j][r] = (unsigned)((row*128 + (j*16 + r16)*2) ^ ((row & 7) << 4));
    }
  const unsigned proff0 = (unsigned)((r16*128      + g*16) ^ ((r16 & 7) << 4));
  const unsigned proff1 = (unsigned)((r16*128 + 64 + g*16) ^ ((r16 & 7) << 4));
  unsigned short* pw = Psm[w];

  const unsigned short* kp = Kh + base + (size_t)r16*DH + g*8;
  const unsigned short* vp = Vt + base + (size_t)r16*N_ + g*8;

  for (int kt = 0; kt < 32; ++kt){
    // S = Q K^T  (16 q-rows x 64 keys per wave)
    f4_t s[4];
    #pragma unroll
    for (int j = 0; j < 4; ++j){
      const bf8_t kb0 = *(const bf8_t*)(kp + (size_t)(kt*64 + j*16)*DH);
      const bf8_t kb1 = *(const bf8_t*)(kp + (size_t)(kt*64 + j*16)*DH + 32);
      f4_t z = {0.f, 0.f, 0.f, 0.f};
      z = __builtin_amdgcn_mfma_f32_16x16x32_bf16(qa[0], kb0, z, 0, 0, 0);
      z = __builtin_amdgcn_mfma_f32_16x16x32_bf16(qa[1], kb1, z, 0, 0, 0);
      s[j] = z;
    }

    // online softmax; rows = g*4+r, row-reduce over the 16 r16-lanes
    float p[4][4], fscale[4];
    #pragma unroll
    for (int r = 0; r < 4; ++r){
      float mx = fmaxf(fmaxf(s[0][r], s[1][r]), fmaxf(s[2][r], s[3][r]));
      mx = fmaxf(mx, __shfl_xor(mx, 1));
      mx = fmaxf(mx, __shfl_xor(mx, 2));
      mx = fmaxf(mx, __shfl_xor(mx, 4));
      mx = fmaxf(mx, __shfl_xor(mx, 8));
      const float mnew = fmaxf(mrow[r], mx);
      fscale[r] = __expf(mrow[r] - mnew);
      mrow[r] = mnew;
      float ps = 0.f;
      #pragma unroll
      for (int j = 0; j < 4; ++j){ p[j][r] = __expf(s[j][r] - mnew); ps += p[j][r]; }
      ps += __shfl_xor(ps, 1); ps += __shfl_xor(ps, 2);
      ps += __shfl_xor(ps, 4); ps += __shfl_xor(ps, 8);
      lrow[r] = lrow[r]*fscale[r] + ps;
    }
    #pragma unroll
    for (int nt = 0; nt < 4; ++nt){
      f4_t o = oacc[nt];
      o[0] *= fscale[0]; o[1] *= fscale[1]; o[2] *= fscale[2]; o[3] *= fscale[3];
      oacc[nt] = o;
    }

    // P -> per-wave LDS (D-layout scatter), re-read as A-frags
    #pragma unroll
    for (int j = 0; j < 4; ++j)
      #pragma unroll
      for (int r = 0; r < 4; ++r)
        *(unsigned short*)((char*)pw + pwoff[j][r]) = f2bf(p[j][r]);
    asm volatile("s_waitcnt lgkmcnt(0)" ::: "memory");
    __builtin_amdgcn_sched_barrier(0);
    bf8_t pa[2];
    pa[0] = *(const bf8_t*)((char*)pw + proff0);
    pa[1] = *(const bf8_t*)((char*)pw + proff1);

    // O += P V  (V^T frags direct from global)
    #pragma unroll
    for (int nt = 0; nt < 4; ++nt){
      const bf8_t vb0 = *(const bf8_t*)(vp + (size_t)nt*16*N_ + kt*64);
      const bf8_t vb1 = *(const bf8_t*)(vp + (size_t)nt*16*N_ + kt*64 + 32);
      oacc[nt] = __builtin_amdgcn_mfma_f32_16x16x32_bf16(pa[0], vb0, oacc[nt], 0, 0, 0);
      oacc[nt] = __builtin_amdgcn_mfma_f32_16x16x32_bf16(pa[1], vb1, oacc[nt], 0, 0, 0);
    }
  }

  // epilogue: O /= l, store [b,n,h*dh] bf16
  const int b = bh >> 3, h = bh & 7;
  #pragma unroll
  for (int nt = 0; nt < 4; ++nt)
    #pragma unroll
    for (int r = 0; r < 4; ++r){
      const int qrow = q0 + g*4 + r;
      Oh[((size_t)(b*N_ + qrow))*INNER + h*DH + nt*16 + r16] = f2bf(oacc[nt][r] / lrow[r]);
    }
}

extern "C" void kernel_launch(void* const* d_in, const int* in_sizes, int n_in,
                              void* d_out, int out_size, void* d_ws, size_t ws_size,
                              hipStream_t stream)
{
  const float* x     = (const float*)d_in[0];
  const float* ln_g  = (const float*)d_in[1];
  const float* ln_b  = (const float*)d_in[2];
  const float* w_qkv = (const float*)d_in[3];  // [512, 1536]
  const float* w_out = (const float*)d_in[4];  // [512, 512]
  const float* b_out = (const float*)d_in[5];
  float* out = (float*)d_out;

  char* ws = (char*)d_ws;
  size_t off = 0;
  auto alloc = [&](size_t bytes) -> void* {
    void* p = ws + off; off += (bytes + 255) & ~(size_t)255; return p;
  };
  float*          sin_t = (float*)alloc((size_t)N_*DH*4);
  float*          cos_t = (float*)alloc((size_t)N_*DH*4);
  unsigned short* wqkvT = (unsigned short*)alloc((size_t)QKVN*DIM*2);   // [1536][512]
  unsigned short* woutT = (unsigned short*)alloc((size_t)DIM*INNER*2);  // [512][512]
  unsigned short* xn    = (unsigned short*)alloc((size_t)ROWS*DIM*2);
  unsigned short* qkv   = (unsigned short*)alloc((size_t)ROWS*QKVN*2);
  unsigned short* Qhb   = (unsigned short*)alloc((size_t)ROWS*INNER*2);
  unsigned short* Khb   = (unsigned short*)alloc((size_t)ROWS*INNER*2);
  unsigned short* Vhb   = (unsigned short*)alloc((size_t)ROWS*INNER*2);
  unsigned short* aout  = xn;   // xn dead after QKV GEMM
  unsigned short* Vtb   = qkv;  // qkv dead after rope_apply; Vt needs 8MB < 24MB

  hipLaunchKernelGGL(ln_kernel, dim3(ROWS), dim3(128), 0, stream, x, ln_g, ln_b, xn);
  hipLaunchKernelGGL(transpose_f32_to_bf16T, dim3(QKVN/32, DIM/32), dim3(256), 0, stream,
                     w_qkv, wqkvT, DIM, QKVN);
  hipLaunchKernelGGL(transpose_f32_to_bf16T, dim3(DIM/32, INNER/32), dim3(256), 0, stream,
                     w_out, woutT, INNER, DIM);
  hipLaunchKernelGGL(rope_table, dim3((N_*DH)/256), dim3(256), 0, stream, sin_t, cos_t);
  hipLaunchKernelGGL((gemm128<1,0>), dim3(ROWS/128, QKVN/128), dim3(256), 0, stream,
                     xn, wqkvT, (void*)qkv, (const float*)nullptr, ROWS, QKVN, DIM);
  hipLaunchKernelGGL(rope_apply, dim3((ROWS*HEADS)/4), dim3(256), 0, stream,
                     qkv, sin_t, cos_t, Qhb, Khb, Vhb);
  hipLaunchKernelGGL(v_transpose, dim3(N_/64, B_*HEADS), dim3(256), 0, stream, Vhb, Vtb);
  hipLaunchKernelGGL(flash_attn2, dim3(B_*HEADS*N_/64), dim3(256), 0, stream,
                     Qhb, Khb, Vtb, aout);
  hipLaunchKernelGGL((gemm128<0,1>), dim3(ROWS/128, DIM/128), dim3(256), 0, stream,
                     aout, woutT, (void*)out, b_out, ROWS, DIM, DIM);
}

// Round 3
// 268.590 us; speedup vs baseline: 1.3648x; 1.3648x over previous
//
#include <hip/hip_runtime.h>
#include <hip/hip_bf16.h>
#include <stdint.h>

#define DIM   512
#define INNER 512
#define HEADS 8
#define DH    64
#define B_    4
#define N_    2048
#define ROWS  (B_*N_)     // 8192
#define QKVN  (3*INNER)   // 1536

typedef __attribute__((ext_vector_type(8))) short bf8_t;  // 8 bf16 (4 VGPRs)
typedef __attribute__((ext_vector_type(4))) float f4_t;   // MFMA C/D

__device__ __forceinline__ unsigned short f2bf(float f){
  union { float f; unsigned u; } x; x.f = f;
  unsigned u = x.u;
  return (unsigned short)((u + 0x7fffu + ((u >> 16) & 1u)) >> 16);  // RTNE
}
__device__ __forceinline__ float bf2f(unsigned short h){
  union { unsigned u; float f; } x; x.u = ((unsigned)h) << 16; return x.f;
}

// ---------------- LayerNorm: fp32 [8192,512] -> bf16 xn ----------------
__global__ __launch_bounds__(128)
void ln_kernel(const float* __restrict__ x, const float* __restrict__ g,
               const float* __restrict__ b, unsigned short* __restrict__ xn)
{
  const int row = blockIdx.x;
  const int t = threadIdx.x;
  const float4 v = ((const float4*)(x + (size_t)row*DIM))[t];
  float s  = v.x + v.y + v.z + v.w;
  float s2 = v.x*v.x + v.y*v.y + v.z*v.z + v.w*v.w;
  #pragma unroll
  for (int d = 32; d >= 1; d >>= 1){ s += __shfl_down(s, d); s2 += __shfl_down(s2, d); }
  __shared__ float ps[2], ps2[2];
  if ((t & 63) == 0){ ps[t >> 6] = s; ps2[t >> 6] = s2; }
  __syncthreads();
  const float mu  = (ps[0] + ps[1]) * (1.f/DIM);
  const float var = (ps2[0] + ps2[1]) * (1.f/DIM) - mu*mu;
  const float rs  = rsqrtf(var + 1e-5f);
  const float4 gm = ((const float4*)g)[t];
  const float4 bt = ((const float4*)b)[t];
  unsigned long long pk =
      (unsigned long long)f2bf((v.x-mu)*rs*gm.x + bt.x)
    | ((unsigned long long)f2bf((v.y-mu)*rs*gm.y + bt.y) << 16)
    | ((unsigned long long)f2bf((v.z-mu)*rs*gm.z + bt.z) << 32)
    | ((unsigned long long)f2bf((v.w-mu)*rs*gm.w + bt.w) << 48);
  *(unsigned long long*)(xn + (size_t)row*DIM + t*4) = pk;
}

// ---------- transpose fp32 W[R][C] -> bf16 WT[C][R] (LDS-tiled) ----------
__global__ __launch_bounds__(256)
void transpose_f32_to_bf16T(const float* __restrict__ W, unsigned short* __restrict__ WT,
                            int R, int C)
{
  __shared__ float tile[32][33];
  const int bc = blockIdx.x*32, br = blockIdx.y*32;
  const int tx = threadIdx.x & 31, ty = threadIdx.x >> 5;  // ty 0..7
  #pragma unroll
  for (int i = 0; i < 32; i += 8) tile[ty+i][tx] = W[(size_t)(br+ty+i)*C + bc+tx];
  __syncthreads();
  #pragma unroll
  for (int i = 0; i < 32; i += 8) WT[(size_t)(bc+ty+i)*R + br+tx] = f2bf(tile[tx][ty+i]);
}

// ---------------- RoPE sin/cos table [2048][64] fp32 ----------------
__global__ __launch_bounds__(256)
void rope_table(float* __restrict__ sin_t, float* __restrict__ cos_t)
{
  const int idx = blockIdx.x*256 + threadIdx.x;     // exactly 2048*64
  const int pos = idx >> 6, i = idx & 63;
  const float freq = expf((float)i * (-9.210340371976184f / 64.f)); // 10000^(-i/64)
  const float ang  = (float)pos * freq;
  sin_t[idx] = sinf(ang);
  cos_t[idx] = cosf(ang);
}

// --------- GEMM: C[M,N] = A[M,K]bf16 * BT[N,K]bf16  (128x128 tile, BK=32) ---------
template<int OUT_BF16, int ADD_BIAS>
__global__ __launch_bounds__(256)
void gemm128(const unsigned short* __restrict__ A, const unsigned short* __restrict__ BT,
             void* __restrict__ Cout, const float* __restrict__ bias, int M, int N, int K)
{
  __shared__ unsigned short Asm_[128*32];
  __shared__ unsigned short Bsm_[128*32];
  const int t = threadIdx.x;
  const int lane = t & 63, w = t >> 6;
  const int g = lane >> 4, r16 = lane & 15;
  const size_t bm = (size_t)blockIdx.x * 128, bn = (size_t)blockIdx.y * 128;
  const int wm = (w >> 1) * 64, wn = (w & 1) * 64;
  f4_t acc[4][4] = {};

  int aoff[4], boff[4];
  #pragma unroll
  for (int m = 0; m < 4; ++m){
    const int row = wm + m*16 + r16;
    aoff[m] = (row*4 + (g ^ ((row >> 1) & 3))) * 16;
    const int col = wn + m*16 + r16;
    boff[m] = (col*4 + (g ^ ((col >> 1) & 3))) * 16;
  }
  int srow[2], scol[2];
  #pragma unroll
  for (int rd = 0; rd < 2; ++rd){
    const int slot = rd*256 + t;
    srow[rd] = slot >> 2;
    scol[rd] = ((slot & 3) ^ ((srow[rd] >> 1) & 3)) * 8;
  }

  for (int k0 = 0; k0 < K; k0 += 32){
    #pragma unroll
    for (int rd = 0; rd < 2; ++rd){
      const unsigned short* ga = A  + (bm + srow[rd])*K + k0 + scol[rd];
      const unsigned short* gb = BT + (bn + srow[rd])*K + k0 + scol[rd];
      __builtin_amdgcn_global_load_lds((const __attribute__((address_space(1))) void*)ga,
          (__attribute__((address_space(3))) void*)((char*)Asm_ + (rd*256 + w*64)*16), 16, 0, 0);
      __builtin_amdgcn_global_load_lds((const __attribute__((address_space(1))) void*)gb,
          (__attribute__((address_space(3))) void*)((char*)Bsm_ + (rd*256 + w*64)*16), 16, 0, 0);
    }
    __syncthreads();
    bf8_t af[4], bfr[4];
    #pragma unroll
    for (int m = 0; m < 4; ++m) af[m]  = *(const bf8_t*)((const char*)Asm_ + aoff[m]);
    #pragma unroll
    for (int n = 0; n < 4; ++n) bfr[n] = *(const bf8_t*)((const char*)Bsm_ + boff[n]);
    #pragma unroll
    for (int m = 0; m < 4; ++m)
      #pragma unroll
      for (int n = 0; n < 4; ++n)
        acc[m][n] = __builtin_amdgcn_mfma_f32_16x16x32_bf16(af[m], bfr[n], acc[m][n], 0, 0, 0);
    __syncthreads();
  }

  #pragma unroll
  for (int m = 0; m < 4; ++m)
    #pragma unroll
    for (int n = 0; n < 4; ++n)
      #pragma unroll
      for (int r = 0; r < 4; ++r){
        const size_t row = bm + wm + m*16 + g*4 + r;
        const size_t col = bn + wn + n*16 + r16;
        float v = acc[m][n][r];
        if (ADD_BIAS) v += bias[col];
        if (OUT_BF16) ((unsigned short*)Cout)[row*N + col] = f2bf(v);
        else          ((float*)Cout)[row*N + col] = v;
      }
}

// ---------- RoPE apply + head relayout: qkv[8192][1536] -> Qh/Kh/Vh [32][2048][64] ----------
// Q is pre-scaled by dh^-0.5 = 0.125 (exponent-exact in bf16).
__global__ __launch_bounds__(256)
void rope_apply(const unsigned short* __restrict__ qkv, const float* __restrict__ sin_t,
                const float* __restrict__ cos_t, unsigned short* __restrict__ Qh,
                unsigned short* __restrict__ Kh, unsigned short* __restrict__ Vh)
{
  const int wid  = blockIdx.x*4 + (threadIdx.x >> 6);   // one wave per (bh, n)
  const int lane = threadIdx.x & 63;
  const int n  = wid & (N_-1);
  const int bh = wid >> 11;
  const int h = bh & 7, b = bh >> 3;
  const size_t src = ((size_t)(b*N_ + n))*QKVN + h*DH + lane;
  const float q = bf2f(qkv[src]);
  const float k = bf2f(qkv[src + INNER]);
  const unsigned short v = qkv[src + 2*INNER];
  const float qm = __shfl(q, (lane + 63) & 63);   // roll(x,1,-1)
  const float km = __shfl(k, (lane + 63) & 63);
  const float sn = sin_t[n*DH + lane], cs = cos_t[n*DH + lane];
  const size_t dst = ((size_t)bh*N_ + n)*DH + lane;
  Qh[dst] = f2bf((q*cs + qm*sn) * 0.125f);
  Kh[dst] = f2bf(k*cs + km*sn);
  Vh[dst] = v;
}

// ---------- V transpose per head: Vh[bh][n][d] -> Vt[bh][d][n] ----------
__global__ __launch_bounds__(256)
void v_transpose(const unsigned short* __restrict__ Vh, unsigned short* __restrict__ Vt)
{
  __shared__ unsigned short tile[64][72];
  const int bh = blockIdx.y, n0 = blockIdx.x*64;
  const int t = threadIdx.x;
  const size_t base = (size_t)bh*N_*DH;
  {
    const int r = t >> 2, seg = t & 3;
    const uint4* src = (const uint4*)(Vh + base + (size_t)(n0 + r)*DH + seg*16);
    *(uint4*)&tile[r][seg*16]     = src[0];
    *(uint4*)&tile[r][seg*16 + 8] = src[1];
  }
  __syncthreads();
  {
    const int d = t & 63, wv = t >> 6;
    unsigned short tmp[16];
    #pragma unroll
    for (int e = 0; e < 16; ++e) tmp[e] = tile[wv*16 + e][d];
    uint4* dst = (uint4*)(Vt + base + (size_t)d*N_ + n0 + wv*16);
    dst[0] = *(uint4*)&tmp[0];
    dst[1] = *(uint4*)&tmp[8];
  }
}

// ---------------- flash attention v3: double-buffered LDS staging ----------------
// K tile [64 key][64 d] and Vt tile [64 d][64 key] staged via global_load_lds with
// PRE-SWIZZLED global source (chunk ^= row&7): LDS dest stays linear (DMA constraint),
// frag ds_read_b128 applies the same XOR -> conflict-free both sides (G21).
// 2-phase pipeline (T3 minimum): STAGE(next) issued before compute(cur), one barrier/tile.
__global__ __launch_bounds__(256)
void flash_attn3(const unsigned short* __restrict__ Qh, const unsigned short* __restrict__ Kh,
                 const unsigned short* __restrict__ Vt, unsigned short* __restrict__ Oh)
{
  __shared__ unsigned short Ksm[2][64*64];   // 8KB x2
  __shared__ unsigned short Vsm[2][64*64];   // 8KB x2
  __shared__ unsigned short Psm[4][16*64];   // per-wave P, 2KB x4
  const int t = threadIdx.x, lane = t & 63, w = t >> 6;
  const int g = lane >> 4, r16 = lane & 15;
  const int i = blockIdx.x;
  const int bh = (i & 7)*4 + (i >> 8);   // 4 heads per XCD -> 2MB K+V in XCD L2
  const int qt = (i >> 3) & 31;
  const size_t base = (size_t)bh * (N_*DH);
  const int q0 = qt*64 + w*16;

  bf8_t qa[2];   // Q A-frags (pre-scaled by 0.125), held for the whole loop
  #pragma unroll
  for (int kc = 0; kc < 2; ++kc)
    qa[kc] = *(const bf8_t*)(Qh + base + (size_t)(q0 + r16)*DH + kc*32 + g*8);

  // staging: slot s = rd*256 + t; row = s>>3 (128B rows), src chunk = (s&7)^(row&7)
  size_t koff[2], voff[2];
  int ldst[2];
  #pragma unroll
  for (int rd = 0; rd < 2; ++rd){
    const int s = rd*256 + t;
    const int row = s >> 3, ch = (s & 7) ^ (row & 7);
    koff[rd] = (size_t)row*DH + ch*8;
    voff[rd] = (size_t)row*N_ + ch*8;
    ldst[rd] = (rd*256 + w*64)*16;   // wave-uniform LDS base for this issue
  }

  f4_t oacc[4] = {};
  float mrow[4] = {-1e30f, -1e30f, -1e30f, -1e30f};
  float lrow[4] = {0.f, 0.f, 0.f, 0.f};

  // kt-invariant P-roundtrip byte offsets
  unsigned pwoff[4][4];
  #pragma unroll
  for (int j = 0; j < 4; ++j)
    #pragma unroll
    for (int r = 0; r < 4; ++r){
      const int row = g*4 + r;
      pwoff[j][r] = (unsigned)((row*128 + (j*16 + r16)*2) ^ ((row & 7) << 4));
    }
  const unsigned proff0 = (unsigned)((r16*128      + g*16) ^ ((r16 & 7) << 4));
  const unsigned proff1 = (unsigned)((r16*128 + 64 + g*16) ^ ((r16 & 7) << 4));
  unsigned short* pw = Psm[w];

  // frag-read byte offsets (kt-invariant): K rows j*16+r16, V rows nt*16+r16
  unsigned kfo[4][2], vfo[4][2];
  #pragma unroll
  for (int j = 0; j < 4; ++j){
    const int row = j*16 + r16, sw = (row & 7) << 4;
    kfo[j][0] = (unsigned)((row*128      + g*16) ^ sw);
    kfo[j][1] = (unsigned)((row*128 + 64 + g*16) ^ sw);
    vfo[j][0] = kfo[j][0];  // same formula (V rows are d)
    vfo[j][1] = kfo[j][1];
  }

  #define STAGE(buf, kt2) do {                                                      \
    const int n0_ = (kt2)*64;                                                       \
    _Pragma("unroll")                                                               \
    for (int rd = 0; rd < 2; ++rd){                                                 \
      __builtin_amdgcn_global_load_lds(                                             \
        (const __attribute__((address_space(1))) void*)(Kh + base + (size_t)n0_*DH + koff[rd]), \
        (__attribute__((address_space(3))) void*)((char*)Ksm[buf] + ldst[rd]), 16, 0, 0); \
      __builtin_amdgcn_global_load_lds(                                             \
        (const __attribute__((address_space(1))) void*)(Vt + base + n0_ + voff[rd]),\
        (__attribute__((address_space(3))) void*)((char*)Vsm[buf] + ldst[rd]), 16, 0, 0); \
    }                                                                               \
  } while (0)

  STAGE(0, 0);
  __syncthreads();   // drains vmcnt before barrier -> tile 0 resident
  int cur = 0;

  for (int kt = 0; kt < 32; ++kt){
    if (kt < 31) STAGE(cur ^ 1, kt + 1);   // loads fly during compute
    const char* Kc = (const char*)Ksm[cur];
    const char* Vc = (const char*)Vsm[cur];

    // S = Q K^T  (16 q-rows x 64 keys per wave)
    f4_t s[4];
    #pragma unroll
    for (int j = 0; j < 4; ++j){
      const bf8_t kb0 = *(const bf8_t*)(Kc + kfo[j][0]);
      const bf8_t kb1 = *(const bf8_t*)(Kc + kfo[j][1]);
      f4_t z = {0.f, 0.f, 0.f, 0.f};
      z = __builtin_amdgcn_mfma_f32_16x16x32_bf16(qa[0], kb0, z, 0, 0, 0);
      z = __builtin_amdgcn_mfma_f32_16x16x32_bf16(qa[1], kb1, z, 0, 0, 0);
      s[j] = z;
    }

    // online softmax; rows = g*4+r, row-reduce over the 16 r16-lanes
    float p[4][4], fscale[4];
    #pragma unroll
    for (int r = 0; r < 4; ++r){
      float mx = fmaxf(fmaxf(s[0][r], s[1][r]), fmaxf(s[2][r], s[3][r]));
      mx = fmaxf(mx, __shfl_xor(mx, 1));
      mx = fmaxf(mx, __shfl_xor(mx, 2));
      mx = fmaxf(mx, __shfl_xor(mx, 4));
      mx = fmaxf(mx, __shfl_xor(mx, 8));
      const float mnew = fmaxf(mrow[r], mx);
      fscale[r] = __expf(mrow[r] - mnew);
      mrow[r] = mnew;
      float ps = 0.f;
      #pragma unroll
      for (int j = 0; j < 4; ++j){ p[j][r] = __expf(s[j][r] - mnew); ps += p[j][r]; }
      ps += __shfl_xor(ps, 1); ps += __shfl_xor(ps, 2);
      ps += __shfl_xor(ps, 4); ps += __shfl_xor(ps, 8);
      lrow[r] = lrow[r]*fscale[r] + ps;
    }
    #pragma unroll
    for (int nt = 0; nt < 4; ++nt){
      f4_t o = oacc[nt];
      o[0] *= fscale[0]; o[1] *= fscale[1]; o[2] *= fscale[2]; o[3] *= fscale[3];
      oacc[nt] = o;
    }

    // P -> per-wave LDS (D-layout scatter), re-read as A-frags
    #pragma unroll
    for (int j = 0; j < 4; ++j)
      #pragma unroll
      for (int r = 0; r < 4; ++r)
        *(unsigned short*)((char*)pw + pwoff[j][r]) = f2bf(p[j][r]);
    asm volatile("s_waitcnt lgkmcnt(0)" ::: "memory");
    __builtin_amdgcn_sched_barrier(0);
    bf8_t pa[2];
    pa[0] = *(const bf8_t*)((char*)pw + proff0);
    pa[1] = *(const bf8_t*)((char*)pw + proff1);

    // O += P V  (V^T frags from LDS)
    #pragma unroll
    for (int nt = 0; nt < 4; ++nt){
      const bf8_t vb0 = *(const bf8_t*)(Vc + vfo[nt][0]);
      const bf8_t vb1 = *(const bf8_t*)(Vc + vfo[nt][1]);
      oacc[nt] = __builtin_amdgcn_mfma_f32_16x16x32_bf16(pa[0], vb0, oacc[nt], 0, 0, 0);
      oacc[nt] = __builtin_amdgcn_mfma_f32_16x16x32_bf16(pa[1], vb1, oacc[nt], 0, 0, 0);
    }

    __syncthreads();   // stage(kt+1) landed + all waves done with buf cur
    cur ^= 1;
  }
  #undef STAGE

  // epilogue: O /= l, store [b,n,h*dh] bf16
  const int b = bh >> 3, h = bh & 7;
  #pragma unroll
  for (int nt = 0; nt < 4; ++nt)
    #pragma unroll
    for (int r = 0; r < 4; ++r){
      const int qrow = q0 + g*4 + r;
      Oh[((size_t)(b*N_ + qrow))*INNER + h*DH + nt*16 + r16] = f2bf(oacc[nt][r] / lrow[r]);
    }
}

extern "C" void kernel_launch(void* const* d_in, const int* in_sizes, int n_in,
                              void* d_out, int out_size, void* d_ws, size_t ws_size,
                              hipStream_t stream)
{
  const float* x     = (const float*)d_in[0];
  const float* ln_g  = (const float*)d_in[1];
  const float* ln_b  = (const float*)d_in[2];
  const float* w_qkv = (const float*)d_in[3];  // [512, 1536]
  const float* w_out = (const float*)d_in[4];  // [512, 512]
  const float* b_out = (const float*)d_in[5];
  float* out = (float*)d_out;

  char* ws = (char*)d_ws;
  size_t off = 0;
  auto alloc = [&](size_t bytes) -> void* {
    void* p = ws + off; off += (bytes + 255) & ~(size_t)255; return p;
  };
  float*          sin_t = (float*)alloc((size_t)N_*DH*4);
  float*          cos_t = (float*)alloc((size_t)N_*DH*4);
  unsigned short* wqkvT = (unsigned short*)alloc((size_t)QKVN*DIM*2);   // [1536][512]
  unsigned short* woutT = (unsigned short*)alloc((size_t)DIM*INNER*2);  // [512][512]
  unsigned short* xn    = (unsigned short*)alloc((size_t)ROWS*DIM*2);
  unsigned short* qkv   = (unsigned short*)alloc((size_t)ROWS*QKVN*2);
  unsigned short* Qhb   = (unsigned short*)alloc((size_t)ROWS*INNER*2);
  unsigned short* Khb   = (unsigned short*)alloc((size_t)ROWS*INNER*2);
  unsigned short* Vhb   = (unsigned short*)alloc((size_t)ROWS*INNER*2);
  unsigned short* aout  = xn;   // xn dead after QKV GEMM
  unsigned short* Vtb   = qkv;  // qkv dead after rope_apply

  hipLaunchKernelGGL(ln_kernel, dim3(ROWS), dim3(128), 0, stream, x, ln_g, ln_b, xn);
  hipLaunchKernelGGL(transpose_f32_to_bf16T, dim3(QKVN/32, DIM/32), dim3(256), 0, stream,
                     w_qkv, wqkvT, DIM, QKVN);
  hipLaunchKernelGGL(transpose_f32_to_bf16T, dim3(DIM/32, INNER/32), dim3(256), 0, stream,
                     w_out, woutT, INNER, DIM);
  hipLaunchKernelGGL(rope_table, dim3((N_*DH)/256), dim3(256), 0, stream, sin_t, cos_t);
  hipLaunchKernelGGL((gemm128<1,0>), dim3(ROWS/128, QKVN/128), dim3(256), 0, stream,
                     xn, wqkvT, (void*)qkv, (const float*)nullptr, ROWS, QKVN, DIM);
  hipLaunchKernelGGL(rope_apply, dim3((ROWS*HEADS)/4), dim3(256), 0, stream,
                     qkv, sin_t, cos_t, Qhb, Khb, Vhb);
  hipLaunchKernelGGL(v_transpose, dim3(N_/64, B_*HEADS), dim3(256), 0, stream, Vhb, Vtb);
  hipLaunchKernelGGL(flash_attn3, dim3(B_*HEADS*N_/64), dim3(256), 0, stream,
                     Qhb, Khb, Vtb, aout);
  hipLaunchKernelGGL((gemm128<0,1>), dim3(ROWS/128, DIM/128), dim3(256), 0, stream,
                     aout, woutT, (void*)out, b_out, ROWS, DIM, DIM);
}

// Round 4
// 211.924 us; speedup vs baseline: 1.7298x; 1.2674x over previous
//
#include <hip/hip_runtime.h>
#include <hip/hip_bf16.h>
#include <stdint.h>

#define DIM   512
#define INNER 512
#define HEADS 8
#define DH    64
#define B_    4
#define N_    2048
#define ROWS  (B_*N_)     // 8192
#define QKVN  (3*INNER)   // 1536

typedef __attribute__((ext_vector_type(8)))  short bf8_t;   // 8 bf16 (4 VGPRs)
typedef __attribute__((ext_vector_type(4)))  float f4_t;    // 16x16 MFMA C/D
typedef __attribute__((ext_vector_type(16))) float f16v;    // 32x32 MFMA C/D

__device__ __forceinline__ unsigned short f2bf(float f){
  union { float f; unsigned u; } x; x.f = f;
  unsigned u = x.u;
  return (unsigned short)((u + 0x7fffu + ((u >> 16) & 1u)) >> 16);  // RTNE
}
__device__ __forceinline__ float bf2f(unsigned short h){
  union { unsigned u; float f; } x; x.u = ((unsigned)h) << 16; return x.f;
}
__device__ __forceinline__ unsigned cvtpk(float lo, float hi){
  unsigned r;
  asm("v_cvt_pk_bf16_f32 %0, %1, %2" : "=v"(r) : "v"(lo), "v"(hi));
  return r;   // low16 = bf16(lo), high16 = bf16(hi)
}

// ---------------- LayerNorm: fp32 [8192,512] -> bf16 xn ----------------
__global__ __launch_bounds__(128)
void ln_kernel(const float* __restrict__ x, const float* __restrict__ g,
               const float* __restrict__ b, unsigned short* __restrict__ xn)
{
  const int row = blockIdx.x;
  const int t = threadIdx.x;
  const float4 v = ((const float4*)(x + (size_t)row*DIM))[t];
  float s  = v.x + v.y + v.z + v.w;
  float s2 = v.x*v.x + v.y*v.y + v.z*v.z + v.w*v.w;
  #pragma unroll
  for (int d = 32; d >= 1; d >>= 1){ s += __shfl_down(s, d); s2 += __shfl_down(s2, d); }
  __shared__ float ps[2], ps2[2];
  if ((t & 63) == 0){ ps[t >> 6] = s; ps2[t >> 6] = s2; }
  __syncthreads();
  const float mu  = (ps[0] + ps[1]) * (1.f/DIM);
  const float var = (ps2[0] + ps2[1]) * (1.f/DIM) - mu*mu;
  const float rs  = rsqrtf(var + 1e-5f);
  const float4 gm = ((const float4*)g)[t];
  const float4 bt = ((const float4*)b)[t];
  unsigned long long pk =
      (unsigned long long)f2bf((v.x-mu)*rs*gm.x + bt.x)
    | ((unsigned long long)f2bf((v.y-mu)*rs*gm.y + bt.y) << 16)
    | ((unsigned long long)f2bf((v.z-mu)*rs*gm.z + bt.z) << 32)
    | ((unsigned long long)f2bf((v.w-mu)*rs*gm.w + bt.w) << 48);
  *(unsigned long long*)(xn + (size_t)row*DIM + t*4) = pk;
}

// ---------- transpose fp32 W[R][C] -> bf16 WT[C][R] (LDS-tiled) ----------
__global__ __launch_bounds__(256)
void transpose_f32_to_bf16T(const float* __restrict__ W, unsigned short* __restrict__ WT,
                            int R, int C)
{
  __shared__ float tile[32][33];
  const int bc = blockIdx.x*32, br = blockIdx.y*32;
  const int tx = threadIdx.x & 31, ty = threadIdx.x >> 5;  // ty 0..7
  #pragma unroll
  for (int i = 0; i < 32; i += 8) tile[ty+i][tx] = W[(size_t)(br+ty+i)*C + bc+tx];
  __syncthreads();
  #pragma unroll
  for (int i = 0; i < 32; i += 8) WT[(size_t)(bc+ty+i)*R + br+tx] = f2bf(tile[tx][ty+i]);
}

// ---------------- RoPE sin/cos table [2048][64] fp32 ----------------
__global__ __launch_bounds__(256)
void rope_table(float* __restrict__ sin_t, float* __restrict__ cos_t)
{
  const int idx = blockIdx.x*256 + threadIdx.x;     // exactly 2048*64
  const int pos = idx >> 6, i = idx & 63;
  const float freq = expf((float)i * (-9.210340371976184f / 64.f)); // 10000^(-i/64)
  const float ang  = (float)pos * freq;
  sin_t[idx] = sinf(ang);
  cos_t[idx] = cosf(ang);
}

// --------- GEMM: C[M,N] = A[M,K]bf16 * BT[N,K]bf16  (128x128 tile, BK=32) ---------
template<int OUT_BF16, int ADD_BIAS>
__global__ __launch_bounds__(256)
void gemm128(const unsigned short* __restrict__ A, const unsigned short* __restrict__ BT,
             void* __restrict__ Cout, const float* __restrict__ bias, int M, int N, int K)
{
  __shared__ unsigned short Asm_[128*32];
  __shared__ unsigned short Bsm_[128*32];
  const int t = threadIdx.x;
  const int lane = t & 63, w = t >> 6;
  const int g = lane >> 4, r16 = lane & 15;
  const size_t bm = (size_t)blockIdx.x * 128, bn = (size_t)blockIdx.y * 128;
  const int wm = (w >> 1) * 64, wn = (w & 1) * 64;
  f4_t acc[4][4] = {};

  int aoff[4], boff[4];
  #pragma unroll
  for (int m = 0; m < 4; ++m){
    const int row = wm + m*16 + r16;
    aoff[m] = (row*4 + (g ^ ((row >> 1) & 3))) * 16;
    const int col = wn + m*16 + r16;
    boff[m] = (col*4 + (g ^ ((col >> 1) & 3))) * 16;
  }
  int srow[2], scol[2];
  #pragma unroll
  for (int rd = 0; rd < 2; ++rd){
    const int slot = rd*256 + t;
    srow[rd] = slot >> 2;
    scol[rd] = ((slot & 3) ^ ((srow[rd] >> 1) & 3)) * 8;
  }

  for (int k0 = 0; k0 < K; k0 += 32){
    #pragma unroll
    for (int rd = 0; rd < 2; ++rd){
      const unsigned short* ga = A  + (bm + srow[rd])*K + k0 + scol[rd];
      const unsigned short* gb = BT + (bn + srow[rd])*K + k0 + scol[rd];
      __builtin_amdgcn_global_load_lds((const __attribute__((address_space(1))) void*)ga,
          (__attribute__((address_space(3))) void*)((char*)Asm_ + (rd*256 + w*64)*16), 16, 0, 0);
      __builtin_amdgcn_global_load_lds((const __attribute__((address_space(1))) void*)gb,
          (__attribute__((address_space(3))) void*)((char*)Bsm_ + (rd*256 + w*64)*16), 16, 0, 0);
    }
    __syncthreads();
    bf8_t af[4], bfr[4];
    #pragma unroll
    for (int m = 0; m < 4; ++m) af[m]  = *(const bf8_t*)((const char*)Asm_ + aoff[m]);
    #pragma unroll
    for (int n = 0; n < 4; ++n) bfr[n] = *(const bf8_t*)((const char*)Bsm_ + boff[n]);
    #pragma unroll
    for (int m = 0; m < 4; ++m)
      #pragma unroll
      for (int n = 0; n < 4; ++n)
        acc[m][n] = __builtin_amdgcn_mfma_f32_16x16x32_bf16(af[m], bfr[n], acc[m][n], 0, 0, 0);
    __syncthreads();
  }

  #pragma unroll
  for (int m = 0; m < 4; ++m)
    #pragma unroll
    for (int n = 0; n < 4; ++n)
      #pragma unroll
      for (int r = 0; r < 4; ++r){
        const size_t row = bm + wm + m*16 + g*4 + r;
        const size_t col = bn + wn + n*16 + r16;
        float v = acc[m][n][r];
        if (ADD_BIAS) v += bias[col];
        if (OUT_BF16) ((unsigned short*)Cout)[row*N + col] = f2bf(v);
        else          ((float*)Cout)[row*N + col] = v;
      }
}

// ---------- RoPE apply + head relayout ----------
// Q pre-scaled by dh^-0.5 * log2(e) (softmax runs in exp2 domain).
__global__ __launch_bounds__(256)
void rope_apply(const unsigned short* __restrict__ qkv, const float* __restrict__ sin_t,
                const float* __restrict__ cos_t, unsigned short* __restrict__ Qh,
                unsigned short* __restrict__ Kh, unsigned short* __restrict__ Vh)
{
  const int wid  = blockIdx.x*4 + (threadIdx.x >> 6);   // one wave per (bh, n)
  const int lane = threadIdx.x & 63;
  const int n  = wid & (N_-1);
  const int bh = wid >> 11;
  const int h = bh & 7, b = bh >> 3;
  const size_t src = ((size_t)(b*N_ + n))*QKVN + h*DH + lane;
  const float q = bf2f(qkv[src]);
  const float k = bf2f(qkv[src + INNER]);
  const unsigned short v = qkv[src + 2*INNER];
  const float qm = __shfl(q, (lane + 63) & 63);   // roll(x,1,-1)
  const float km = __shfl(k, (lane + 63) & 63);
  const float sn = sin_t[n*DH + lane], cs = cos_t[n*DH + lane];
  const size_t dst = ((size_t)bh*N_ + n)*DH + lane;
  Qh[dst] = f2bf((q*cs + qm*sn) * 0.18033688011112042f);  // 0.125 * log2(e)
  Kh[dst] = f2bf(k*cs + km*sn);
  Vh[dst] = v;
}

// ---------- V transpose per head: Vh[bh][n][d] -> Vt[bh][d][n] ----------
__global__ __launch_bounds__(256)
void v_transpose(const unsigned short* __restrict__ Vh, unsigned short* __restrict__ Vt)
{
  __shared__ unsigned short tile[64][72];
  const int bh = blockIdx.y, n0 = blockIdx.x*64;
  const int t = threadIdx.x;
  const size_t base = (size_t)bh*N_*DH;
  {
    const int r = t >> 2, seg = t & 3;
    const uint4* src = (const uint4*)(Vh + base + (size_t)(n0 + r)*DH + seg*16);
    *(uint4*)&tile[r][seg*16]     = src[0];
    *(uint4*)&tile[r][seg*16 + 8] = src[1];
  }
  __syncthreads();
  {
    const int d = t & 63, wv = t >> 6;
    unsigned short tmp[16];
    #pragma unroll
    for (int e = 0; e < 16; ++e) tmp[e] = tile[wv*16 + e][d];
    uint4* dst = (uint4*)(Vt + base + (size_t)d*N_ + n0 + wv*16);
    dst[0] = *(uint4*)&tmp[0];
    dst[1] = *(uint4*)&tmp[8];
  }
}

// ---------------- flash attention v4: swapped QK^T, 32x32 MFMA, in-reg softmax ----------------
// Per wave: 32 q-rows, KV tiles of 64. S^T = mfma(A=K, B=Q) -> lane owns q-col = lane&31,
// k-rows (reg&3)+8*(reg>>2)+4*hi (+32*kb). Softmax fully in-register (1 shfl_xor(32) per
// reduce). P -> PV B-frags via cvt_pk + shfl_xor(32) (no LDS, no fences). K/V staged to LDS
// double-buffered via global_load_lds with pre-swizzled source (round-3 verified pattern).
__global__ __launch_bounds__(256)
void flash_attn4(const unsigned short* __restrict__ Qh, const unsigned short* __restrict__ Kh,
                 const unsigned short* __restrict__ Vt, unsigned short* __restrict__ Oh)
{
  __shared__ unsigned short Ksm[2][64*64];   // [key][d], 8KB x2
  __shared__ unsigned short Vsm[2][64*64];   // [d][key], 8KB x2
  const int t = threadIdx.x, lane = t & 63, w = t >> 6;
  const int l31 = lane & 31, hi = lane >> 5;
  const int i = blockIdx.x;
  const int bh = (i & 7)*4 + (i >> 7);      // 4 heads per XCD
  const int qt = (i >> 3) & 15;
  const size_t base = (size_t)bh * (N_*DH);
  const int q0w = qt*128 + w*32;

  // Q B-frags: col=l31 (q), k-elems d = dc*16 + hi*8 + e
  bf8_t qb[4];
  #pragma unroll
  for (int dc = 0; dc < 4; ++dc)
    qb[dc] = *(const bf8_t*)(Qh + base + (size_t)(q0w + l31)*DH + dc*16 + hi*8);

  // staging: slot s = rd*256 + t; row = s>>3 (128B rows), src chunk = (s&7)^(row&7)
  size_t koff[2], voff[2];
  int ldst[2];
  #pragma unroll
  for (int rd = 0; rd < 2; ++rd){
    const int s = rd*256 + t;
    const int row = s >> 3, ch = (s & 7) ^ (row & 7);
    koff[rd] = (size_t)row*DH + ch*8;
    voff[rd] = (size_t)row*N_ + ch*8;
    ldst[rd] = (rd*256 + w*64)*16;
  }

  // frag read offsets (shared K/V formula): row = blk*32 + l31, chunk c=0..7
  unsigned fro[2][8];
  #pragma unroll
  for (int blk = 0; blk < 2; ++blk)
    #pragma unroll
    for (int c = 0; c < 8; ++c)
      fro[blk][c] = (unsigned)((blk*32 + l31)*128 + ((c) ^ (l31 & 7))*16);

  f16v o[2]; o[0] = (f16v)0.0f; o[1] = (f16v)0.0f;
  float mrow = -1e30f, lrow = 0.f;

  #define STAGE(buf, kt2) do {                                                      \
    const int n0_ = (kt2)*64;                                                       \
    _Pragma("unroll")                                                               \
    for (int rd = 0; rd < 2; ++rd){                                                 \
      __builtin_amdgcn_global_load_lds(                                             \
        (const __attribute__((address_space(1))) void*)(Kh + base + (size_t)n0_*DH + koff[rd]), \
        (__attribute__((address_space(3))) void*)((char*)Ksm[buf] + ldst[rd]), 16, 0, 0); \
      __builtin_amdgcn_global_load_lds(                                             \
        (const __attribute__((address_space(1))) void*)(Vt + base + n0_ + voff[rd]),\
        (__attribute__((address_space(3))) void*)((char*)Vsm[buf] + ldst[rd]), 16, 0, 0); \
    }                                                                               \
  } while (0)

  STAGE(0, 0);
  __syncthreads();
  int cur = 0;

  for (int kt = 0; kt < 32; ++kt){
    if (kt < 31) STAGE(cur ^ 1, kt + 1);
    const char* Kc = (const char*)Ksm[cur];
    const char* Vc = (const char*)Vsm[cur];

    // S^T = K Q^T : acc s[kb] covers k-rows kb*32..+31 for this lane's q-col
    f16v s0 = (f16v)0.0f, s1 = (f16v)0.0f;
    #pragma unroll
    for (int dc = 0; dc < 4; ++dc){
      const bf8_t ka0 = *(const bf8_t*)(Kc + fro[0][dc*2 + hi]);
      const bf8_t ka1 = *(const bf8_t*)(Kc + fro[1][dc*2 + hi]);
      s0 = __builtin_amdgcn_mfma_f32_32x32x16_bf16(ka0, qb[dc], s0, 0, 0, 0);
      s1 = __builtin_amdgcn_mfma_f32_32x32x16_bf16(ka1, qb[dc], s1, 0, 0, 0);
    }

    // ---- in-register online softmax (exp2 domain; Q pre-scaled by 0.125*log2e) ----
    float tm = s0[0];
    #pragma unroll
    for (int r = 1; r < 16; ++r) tm = fmaxf(tm, s0[r]);
    #pragma unroll
    for (int r = 0; r < 16; ++r) tm = fmaxf(tm, s1[r]);
    tm = fmaxf(tm, __shfl_xor(tm, 32));
    if (!__all(tm <= mrow + 11.5f)){            // defer-max (T13), thr = 8*log2e
      const float mnew = fmaxf(mrow, tm);
      const float fs = exp2f(mrow - mnew);
      #pragma unroll
      for (int r = 0; r < 16; ++r){ o[0][r] *= fs; o[1][r] *= fs; }
      lrow *= fs;
      mrow = mnew;
    }
    float p0[16], p1[16];
    float ps = 0.f;
    #pragma unroll
    for (int r = 0; r < 16; ++r){ p0[r] = exp2f(s0[r] - mrow); ps += p0[r]; }
    #pragma unroll
    for (int r = 0; r < 16; ++r){ p1[r] = exp2f(s1[r] - mrow); ps += p1[r]; }
    ps += __shfl_xor(ps, 32);
    lrow += ps;

    // ---- pack P to bf16 words and exchange halves ----
    // held value (kb, reg r) is P[q, k] with k = kb*32 + 8*(r>>2) + (r&3) + 4*hi
    unsigned wds[2][4][2], swp[2][4][2];
    #pragma unroll
    for (int R = 0; R < 4; ++R){
      wds[0][R][0] = cvtpk(p0[R*4+0], p0[R*4+1]);
      wds[0][R][1] = cvtpk(p0[R*4+2], p0[R*4+3]);
      wds[1][R][0] = cvtpk(p1[R*4+0], p1[R*4+1]);
      wds[1][R][1] = cvtpk(p1[R*4+2], p1[R*4+3]);
    }
    #pragma unroll
    for (int kb = 0; kb < 2; ++kb)
      #pragma unroll
      for (int R = 0; R < 4; ++R){
        swp[kb][R][0] = __shfl_xor(wds[kb][R][0], 32);
        swp[kb][R][1] = __shfl_xor(wds[kb][R][1], 32);
      }

    // ---- PV: O^T += V^T P^T ----
    // B-frag(kc) at lane (q,hi) needs k = kc*16 + hi*8 + e.
    // octet t0=2kc (hi=0 path), t1=2kc+1 (hi=1 path); kb=t>>2, R=t&3.
    #pragma unroll
    for (int kc = 0; kc < 4; ++kc){
      const int kbA = (2*kc) >> 2,     RA = (2*kc) & 3;
      const int kbB = (2*kc + 1) >> 2, RB = (2*kc + 1) & 3;
      union { unsigned u[4]; bf8_t b; } pb;
      pb.u[0] = hi ? swp[kbB][RB][0] : wds[kbA][RA][0];   // e0,e1 (from hi'=0 lane)
      pb.u[1] = hi ? swp[kbB][RB][1] : wds[kbA][RA][1];   // e2,e3
      pb.u[2] = hi ? wds[kbB][RB][0] : swp[kbA][RA][0];   // e4,e5 (from hi'=1 lane)
      pb.u[3] = hi ? wds[kbB][RB][1] : swp[kbA][RA][1];   // e6,e7
      const bf8_t va0 = *(const bf8_t*)(Vc + fro[0][kc*2 + hi]);
      const bf8_t va1 = *(const bf8_t*)(Vc + fro[1][kc*2 + hi]);
      o[0] = __builtin_amdgcn_mfma_f32_32x32x16_bf16(va0, pb.b, o[0], 0, 0, 0);
      o[1] = __builtin_amdgcn_mfma_f32_32x32x16_bf16(va1, pb.b, o[1], 0, 0, 0);
    }

    __syncthreads();
    cur ^= 1;
  }
  #undef STAGE

  // epilogue: O^T acc -> O[q][d], divide by l, bf16 store
  // o[db] reg r: d = db*32 + 8*(r>>2) + (r&3) + 4*hi, q = l31
  const int b = bh >> 3, h = bh & 7;
  const float rl = 1.0f / lrow;
  unsigned short* ob = Oh + ((size_t)(b*N_ + q0w + l31))*INNER + h*DH + 4*hi;
  #pragma unroll
  for (int db = 0; db < 2; ++db)
    #pragma unroll
    for (int R = 0; R < 4; ++R){
      const unsigned v0 = cvtpk(o[db][R*4+0]*rl, o[db][R*4+1]*rl);
      const unsigned v1 = cvtpk(o[db][R*4+2]*rl, o[db][R*4+3]*rl);
      *(unsigned*)(ob + db*32 + 8*R)     = v0;
      *(unsigned*)(ob + db*32 + 8*R + 2) = v1;
    }
}

extern "C" void kernel_launch(void* const* d_in, const int* in_sizes, int n_in,
                              void* d_out, int out_size, void* d_ws, size_t ws_size,
                              hipStream_t stream)
{
  const float* x     = (const float*)d_in[0];
  const float* ln_g  = (const float*)d_in[1];
  const float* ln_b  = (const float*)d_in[2];
  const float* w_qkv = (const float*)d_in[3];  // [512, 1536]
  const float* w_out = (const float*)d_in[4];  // [512, 512]
  const float* b_out = (const float*)d_in[5];
  float* out = (float*)d_out;

  char* ws = (char*)d_ws;
  size_t off = 0;
  auto alloc = [&](size_t bytes) -> void* {
    void* p = ws + off; off += (bytes + 255) & ~(size_t)255; return p;
  };
  float*          sin_t = (float*)alloc((size_t)N_*DH*4);
  float*          cos_t = (float*)alloc((size_t)N_*DH*4);
  unsigned short* wqkvT = (unsigned short*)alloc((size_t)QKVN*DIM*2);   // [1536][512]
  unsigned short* woutT = (unsigned short*)alloc((size_t)DIM*INNER*2);  // [512][512]
  unsigned short* xn    = (unsigned short*)alloc((size_t)ROWS*DIM*2);
  unsigned short* qkv   = (unsigned short*)alloc((size_t)ROWS*QKVN*2);
  unsigned short* Qhb   = (unsigned short*)alloc((size_t)ROWS*INNER*2);
  unsigned short* Khb   = (unsigned short*)alloc((size_t)ROWS*INNER*2);
  unsigned short* Vhb   = (unsigned short*)alloc((size_t)ROWS*INNER*2);
  unsigned short* aout  = xn;   // xn dead after QKV GEMM
  unsigned short* Vtb   = qkv;  // qkv dead after rope_apply

  hipLaunchKernelGGL(ln_kernel, dim3(ROWS), dim3(128), 0, stream, x, ln_g, ln_b, xn);
  hipLaunchKernelGGL(transpose_f32_to_bf16T, dim3(QKVN/32, DIM/32), dim3(256), 0, stream,
                     w_qkv, wqkvT, DIM, QKVN);
  hipLaunchKernelGGL(transpose_f32_to_bf16T, dim3(DIM/32, INNER/32), dim3(256), 0, stream,
                     w_out, woutT, INNER, DIM);
  hipLaunchKernelGGL(rope_table, dim3((N_*DH)/256), dim3(256), 0, stream, sin_t, cos_t);
  hipLaunchKernelGGL((gemm128<1,0>), dim3(ROWS/128, QKVN/128), dim3(256), 0, stream,
                     xn, wqkvT, (void*)qkv, (const float*)nullptr, ROWS, QKVN, DIM);
  hipLaunchKernelGGL(rope_apply, dim3((ROWS*HEADS)/4), dim3(256), 0, stream,
                     qkv, sin_t, cos_t, Qhb, Khb, Vhb);
  hipLaunchKernelGGL(v_transpose, dim3(N_/64, B_*HEADS), dim3(256), 0, stream, Vhb, Vtb);
  hipLaunchKernelGGL(flash_attn4, dim3(512), dim3(256), 0, stream,
                     Qhb, Khb, Vtb, aout);
  hipLaunchKernelGGL((gemm128<0,1>), dim3(ROWS/128, DIM/128), dim3(256), 0, stream,
                     aout, woutT, (void*)out, b_out, ROWS, DIM, DIM);
}